// Round 9
// baseline (226.172 us; speedup 1.0000x reference)
//
#include <hip/hip_runtime.h>
#include <stdint.h>

#define B_ROWS 4096
#define L_FEAT 256
#define VOCAB  8192
#define ROWB   (VOCAB / 2)      // 4096 data bytes per row in fp4 (2 elems/byte)
#define ROWSTRIDE 4352          // padded stride (17*256): breaks power-of-2
                                // channel camping -- 32 rows/staging-instr now
                                // spread across channels instead of one
#define BM 128
#define BN 128
#define BKE 128                 // K elements per step (2 MFMA-K)
#define BKB 64                  // K bytes per step per row
#define NSTEP (VOCAB / BKE)     // 64

typedef __attribute__((ext_vector_type(4)))  int   intx4;
typedef __attribute__((ext_vector_type(8)))  int   intx8;
typedef __attribute__((ext_vector_type(4)))  float floatx4;
typedef __attribute__((ext_vector_type(16))) float floatx16;

// fp4 operand: HW reads only v[0:3] of the 8-reg A/B field (FMT=4).
// Upper half = undef lanes -> no register copies (r7/r8 verified the HW
// ignores the upper regs; -1 shuffle indices let regalloc alias freely).
__device__ __forceinline__ intx8 widen(intx4 v) {
  return __builtin_shufflevector(v, v, 0, 1, 2, 3, -1, -1, -1, -1);
}

__device__ __forceinline__ void async_copy16(const void* gsrc, void* ldst) {
  __builtin_amdgcn_global_load_lds(
      (const __attribute__((address_space(1))) void*)gsrc,
      (__attribute__((address_space(3))) void*)ldst, 16, 0, 0);
}

// ---------------- kernel 1: fused zero+scatter+sizes (fp4, 4 rows/block) -----
// (verified rounds 6-8; now writes rows at the padded ROWSTRIDE)
__global__ __launch_bounds__(256) void presence_kernel(
    const int* __restrict__ f,
    uint32_t* __restrict__ P,     // fp4 presence, ROWSTRIDE bytes per row
    float* __restrict__ sizes) {
  __shared__ uint32_t rw[4][VOCAB / 8];   // 4 x 1024 words = 16 KB
  const int rbase = blockIdx.x * 4;
  const int tid = threadIdx.x;

  uint4* rp4 = (uint4*)&rw[0][0];         // 1024 uint4
  const uint4 z = make_uint4(0u, 0u, 0u, 0u);
  #pragma unroll
  for (int j = 0; j < 4; ++j) rp4[tid + j * 256] = z;
  __syncthreads();

  #pragma unroll
  for (int r = 0; r < 4; ++r) {
    const int v = f[(rbase + r) * L_FEAT + tid];     // coalesced
    atomicOr(&rw[r][v >> 3], 0x2u << ((v & 7) * 4)); // fp4 nibble 1.0; dups ok
  }
  __syncthreads();

  const int w = tid >> 6, lane = tid & 63;           // wave w owns row rbase+w
  uint4* op4 = (uint4*)(P + (size_t)(rbase + w) * (ROWSTRIDE / 4));
  const uint4* sp4 = (const uint4*)&rw[w][0];        // 256 uint4
  int cnt = 0;
  #pragma unroll
  for (int q = 0; q < 4; ++q) {
    const uint4 x = sp4[lane + q * 64];
    op4[lane + q * 64] = x;
    cnt += __popc(x.x & 0x22222222u) + __popc(x.y & 0x22222222u) +
           __popc(x.z & 0x22222222u) + __popc(x.w & 0x22222222u);
  }
  #pragma unroll
  for (int off = 32; off > 0; off >>= 1) cnt += __shfl_down(cnt, off);
  if (lane == 0) sizes[rbase + w] = (float)cnt;
}

// ---------------- kernel 2: inter = P·P^T (fp4 MX MFMA) + Jaccard + mirror ---
// Round-9 = round-8's simple verified schedule (2 buffers, fat BK=128 steps,
// ONE __syncthreads per step) with the CHANNEL-CAMPING FIX:
//   rounds 0-8 all staged N rows at a power-of-2 stride per instruction
//   (fp4: 32 rows x 4096 B) -> all lines of one staging op map to the same
//   L2 channel/set -> ~32-way serialization; this self-inflicted latency is
//   why every schedule variant idled (MfmaUtil <10% with all pipes idle).
//   ROWSTRIDE=4352 (17*256) walks the channel space row-to-row instead.
__global__ __launch_bounds__(256) void gemm_kernel(
    const unsigned char* __restrict__ P,
    const float* __restrict__ sizes,
    float* __restrict__ out) {
  // XCD swizzle (528 = 8*66 -> bijective) then triangle decode, bx >= by
  int bid = blockIdx.x;
  bid = (bid & 7) * 66 + (bid >> 3);
  int b = bid, by = 0, rem = 32;
  while (b >= rem) { b -= rem; ++by; --rem; }
  const int bx = by + b;
  const int iBase = by * BM;   // output rows
  const int jBase = bx * BN;   // output cols

  // chunk(c) = (frag f = c>>1, kk = c&1): 1 KB, lane-linear
  __shared__ __align__(16) unsigned char As[2][8192];  // 8 chunks x 1 KB
  __shared__ __align__(16) unsigned char Bs[2][8192];

  const int tid  = threadIdx.x;
  const int wave = tid >> 6, lane = tid & 63;
  const int wm = wave >> 1, wn = wave & 1;   // 2x2 wave grid, each wave 64x64
  const int r31 = lane & 31, khalf = lane >> 5;

  floatx16 acc[2][2];
  #pragma unroll
  for (int ai = 0; ai < 2; ++ai)
    #pragma unroll
    for (int ci = 0; ci < 2; ++ci)
      #pragma unroll
      for (int e = 0; e < 16; ++e) acc[ai][ci][e] = 0.f;

  // staging: wave w copies chunks {w, w+4} of A and of B (4 ops/wave/step).
  // chunk c source for lane l: row (c>>1)*32 + (l&31), bytes
  // k0b + (c&1)*32 + (l>>5)*16; LDS dst = chunk_base + lane*16 (r6-verified).
  const int c0 = wave, c1 = wave + 4;
  const unsigned char* srcA0 =
      P + (size_t)(iBase + (c0 >> 1) * 32 + r31) * ROWSTRIDE + (c0 & 1) * 32 + khalf * 16;
  const unsigned char* srcA1 =
      P + (size_t)(iBase + (c1 >> 1) * 32 + r31) * ROWSTRIDE + (c1 & 1) * 32 + khalf * 16;
  const unsigned char* srcB0 =
      P + (size_t)(jBase + (c0 >> 1) * 32 + r31) * ROWSTRIDE + (c0 & 1) * 32 + khalf * 16;
  const unsigned char* srcB1 =
      P + (size_t)(jBase + (c1 >> 1) * 32 + r31) * ROWSTRIDE + (c1 & 1) * 32 + khalf * 16;

  #define STAGE(buf, k0b)                                                     \
    {                                                                         \
      async_copy16(srcA0 + (k0b), &As[buf][c0 * 1024]);                       \
      async_copy16(srcA1 + (k0b), &As[buf][c1 * 1024]);                       \
      async_copy16(srcB0 + (k0b), &Bs[buf][c0 * 1024]);                       \
      async_copy16(srcB1 + (k0b), &Bs[buf][c1 * 1024]);                       \
    }

  STAGE(0, 0);          // prologue: stage step 0
  __syncthreads();      // (drains vmcnt0 — once, outside the loop)

  int cur = 0;
  for (int i = 0; i < NSTEP; ++i) {
    // fragment reads for step i: lane-linear ds_read_b128, conflict-free
    intx4 a4[2][2], b4[2][2];   // [tm|tn][kk]
    #pragma unroll
    for (int t = 0; t < 2; ++t)
      #pragma unroll
      for (int kk = 0; kk < 2; ++kk) {
        a4[t][kk] = *(const intx4*)
            &As[cur][((wm * 2 + t) * 2 + kk) * 1024 + lane * 16];
        b4[t][kk] = *(const intx4*)
            &Bs[cur][((wn * 2 + t) * 2 + kk) * 1024 + lane * 16];
      }

    // stage step i+1 into the other buffer (wraps harmlessly at the end);
    // in flight for the whole step, drained by the barrier below.
    // k-offset stays within the 4096 data bytes of each padded row.
    STAGE(cur ^ 1, ((i + 1) * BKB) & (ROWB - 1));

    __builtin_amdgcn_s_setprio(1);
    #pragma unroll
    for (int kk = 0; kk < 2; ++kk) {
      const intx8 A0 = widen(a4[0][kk]), A1 = widen(a4[1][kk]);
      const intx8 B0 = widen(b4[0][kk]), B1 = widen(b4[1][kk]);
      acc[0][0] = __builtin_amdgcn_mfma_scale_f32_32x32x64_f8f6f4(
          A0, B0, acc[0][0], 4, 4, 0, 127, 0, 127);
      acc[0][1] = __builtin_amdgcn_mfma_scale_f32_32x32x64_f8f6f4(
          A0, B1, acc[0][1], 4, 4, 0, 127, 0, 127);
      acc[1][0] = __builtin_amdgcn_mfma_scale_f32_32x32x64_f8f6f4(
          A1, B0, acc[1][0], 4, 4, 0, 127, 0, 127);
      acc[1][1] = __builtin_amdgcn_mfma_scale_f32_32x32x64_f8f6f4(
          A1, B1, acc[1][1], 4, 4, 0, 127, 0, 127);
    }
    __builtin_amdgcn_s_setprio(0);

    __syncthreads();    // one barrier per step: WAR+RAW for both buffers
    cur ^= 1;
  }

  // epilogue (verified rounds 5-8): sim = -inter/(|A_i|+|A_j|-inter) + mirror.
  // 32x32 C layout: col = lane&31, row = (reg&3) + 8*(reg>>2) + 4*(lane>>5).
  #pragma unroll
  for (int tm = 0; tm < 2; ++tm) {
    const int rowb = iBase + wm * 64 + tm * 32 + 4 * khalf;
    #pragma unroll
    for (int tn = 0; tn < 2; ++tn) {
      const int colb = jBase + wn * 64 + tn * 32 + r31;
      const float sj = sizes[colb];
      #pragma unroll
      for (int q = 0; q < 4; ++q) {           // reg quads: rows rq..rq+3
        const int rq = rowb + 8 * q;
        floatx4 tv;
        #pragma unroll
        for (int j = 0; j < 4; ++j) {
          const float inter = acc[tm][tn][4 * q + j];
          const float u = sizes[rq + j] + sj - inter;
          tv[j] = (u != 0.f) ? (-inter / u) : 0.f;
        }
        __builtin_nontemporal_store(tv[0], &out[(size_t)(rq + 0) * B_ROWS + colb]);
        __builtin_nontemporal_store(tv[1], &out[(size_t)(rq + 1) * B_ROWS + colb]);
        __builtin_nontemporal_store(tv[2], &out[(size_t)(rq + 2) * B_ROWS + colb]);
        __builtin_nontemporal_store(tv[3], &out[(size_t)(rq + 3) * B_ROWS + colb]);
        // mirrored: 4 row-values contiguous in the transposed row (16B-aligned)
        __builtin_nontemporal_store(tv, (floatx4*)&out[(size_t)colb * B_ROWS + rq]);
      }
    }
  }
}

// ---------------- launcher ---------------------------------------------------
extern "C" void kernel_launch(void* const* d_in, const int* in_sizes, int n_in,
                              void* d_out, int out_size, void* d_ws, size_t ws_size,
                              hipStream_t stream) {
  const int* features = (const int*)d_in[0];
  float* out = (float*)d_out;
  uint32_t* P = (uint32_t*)d_ws;                    // 17.8 MB fp4 (padded rows)
  float* sizes = (float*)((char*)d_ws + (size_t)B_ROWS * ROWSTRIDE);  // +16 KB

  presence_kernel<<<B_ROWS / 4, 256, 0, stream>>>(features, P, sizes);
  gemm_kernel<<<528, 256, 0, stream>>>((const unsigned char*)P, sizes, out);
}

// Round 10
// 167.705 us; speedup vs baseline: 1.3486x; 1.3486x over previous
//
#include <hip/hip_runtime.h>
#include <stdint.h>

#define B_ROWS 4096
#define L_FEAT 256
#define VOCAB  8192
#define ROWB   (VOCAB / 2)      // 4096 data bytes per row (fp4, 2 elems/byte)
#define FRAG   1024             // one MFMA operand fragment: 32 rows x 64 elems
#define KCHUNKS (VOCAB / 64)    // 128 fragments along K per 32-row group
#define GBYTES  (KCHUNKS * FRAG)  // 128 KB per 32-row group
#define NSTEP  128              // K steps of 64 elems

typedef __attribute__((ext_vector_type(4)))  int   intx4;
typedef __attribute__((ext_vector_type(8)))  int   intx8;
typedef __attribute__((ext_vector_type(4)))  float floatx4;
typedef __attribute__((ext_vector_type(16))) float floatx16;

// fp4 operand: HW reads only v[0:3] of the 8-reg A/B field (FMT=4); upper
// half undef (verified r9: passed, absmax 0).
__device__ __forceinline__ intx8 widen(intx4 v) {
  return __builtin_shufflevector(v, v, 0, 1, 2, 3, -1, -1, -1, -1);
}

// ---------------- kernel 1: presence in PANEL (MFMA-fragment) layout ---------
// 4 rows/block. Phase 1-2 as verified (LDS bitmap + atomicOr scatter).
// Phase 3 writes the panel layout: fragment (g,kc) holds rows [32g,32g+32) x
// k-elems [64kc,64kc+64), byte = (g*128+kc)*1024 + ((row&31)+32*half)*16,
// half = which 16B of the row's 32B k-chunk. Block contributes 4 row-slots
// per fragment -> 64B contiguous chunks (4 lanes each), 1024 uint4 writes.
__global__ __launch_bounds__(256) void presence_kernel(
    const int* __restrict__ f,
    uint32_t* __restrict__ P,     // fp4 presence, panel layout (16 MB)
    float* __restrict__ sizes) {
  __shared__ uint32_t rw[4][VOCAB / 8];   // 4 x 1024 words = 16 KB
  const int rbase = blockIdx.x * 4;
  const int tid = threadIdx.x;

  uint4* rp4 = (uint4*)&rw[0][0];         // 1024 uint4
  const uint4 z = make_uint4(0u, 0u, 0u, 0u);
  #pragma unroll
  for (int j = 0; j < 4; ++j) rp4[tid + j * 256] = z;
  __syncthreads();

  #pragma unroll
  for (int r = 0; r < 4; ++r) {
    const int v = f[(rbase + r) * L_FEAT + tid];     // coalesced
    atomicOr(&rw[r][v >> 3], 0x2u << ((v & 7) * 4)); // fp4 nibble 1.0; dups ok
  }
  __syncthreads();

  // panel write: 1024 chunks of 16B; chunk c -> kc=c>>3, half=(c>>2)&1, ro=c&3
  const int g = blockIdx.x >> 3;
  const int slotBase = (blockIdx.x & 7) * 4;   // row slot within 32-row group
  char* Pg = (char*)P + (size_t)g * GBYTES;
  #pragma unroll
  for (int j = 0; j < 4; ++j) {
    const int c  = tid + j * 256;
    const int kc = c >> 3, h = (c >> 2) & 1, ro = c & 3;
    const uint4 val = *(const uint4*)&rw[ro][kc * 8 + h * 4];
    *(uint4*)(Pg + kc * FRAG + (slotBase + ro + 32 * h) * 16) = val;
  }

  // sizes: wave w popcounts row w (reads rw only; no extra sync needed
  // beyond the one above since rw is read-only now)
  const int w = tid >> 6, lane = tid & 63;
  const uint4* sp4 = (const uint4*)&rw[w][0];        // 256 uint4
  int cnt = 0;
  #pragma unroll
  for (int q = 0; q < 4; ++q) {
    const uint4 x = sp4[lane + q * 64];
    cnt += __popc(x.x & 0x22222222u) + __popc(x.y & 0x22222222u) +
           __popc(x.z & 0x22222222u) + __popc(x.w & 0x22222222u);
  }
  #pragma unroll
  for (int off = 32; off > 0; off >>= 1) cnt += __shfl_down(cnt, off);
  if (lane == 0) sizes[rbase + w] = (float)cnt;
}

// ---------------- kernel 2: inter = P·P^T (fp4 MX MFMA) + Jaccard + mirror ---
// Round-10: NO LDS, NO barriers. Panel layout makes each MFMA operand ONE
// fully-coalesced 1KB global_load_dwordx4 (lane*16, contiguous) -> the
// stage->LDS->barrier structure (2x overhead in every r0-r9 variant) is gone,
// and r4/r7's strided-overfetch failure mode is gone (1 line-run per load).
// Compiler's dependency-driven counted vmcnt pipelines the unroll-4 ring
// (literal indices only -- r7's spill came from the full-128 unroll).
__global__ __launch_bounds__(256, 2) void gemm_kernel(
    const unsigned char* __restrict__ P,
    const float* __restrict__ sizes,
    float* __restrict__ out) {
  // XCD swizzle (528 = 8*66 -> bijective) then triangle decode, bx >= by
  int bid = blockIdx.x;
  bid = (bid & 7) * 66 + (bid >> 3);
  int b = bid, by = 0, rem = 32;
  while (b >= rem) { b -= rem; ++by; --rem; }
  const int bx = by + b;

  const int tid  = threadIdx.x;
  const int wave = tid >> 6, lane = tid & 63;
  const int wm = wave >> 1, wn = wave & 1;   // 2x2 wave grid, each wave 64x64
  const int r31 = lane & 31, khalf = lane >> 5;

  const int iB = by * 128 + wm * 64;   // this wave's output rows
  const int jB = bx * 128 + wn * 64;   // this wave's output cols

  // fragment base pointers (advance +4096 per 4-step body)
  const unsigned char* pA0 = P + (size_t)(by * 4 + wm * 2 + 0) * GBYTES + lane * 16;
  const unsigned char* pA1 = P + (size_t)(by * 4 + wm * 2 + 1) * GBYTES + lane * 16;
  const unsigned char* pB0 = P + (size_t)(bx * 4 + wn * 2 + 0) * GBYTES + lane * 16;
  const unsigned char* pB1 = P + (size_t)(bx * 4 + wn * 2 + 1) * GBYTES + lane * 16;

  floatx16 acc[2][2];
  #pragma unroll
  for (int ai = 0; ai < 2; ++ai)
    #pragma unroll
    for (int ci = 0; ci < 2; ++ci)
      #pragma unroll
      for (int e = 0; e < 16; ++e) acc[ai][ci][e] = 0.f;

  intx4 a0[4], a1[4], b0[4], b1[4];   // 4-step register ring, literal indices

  #pragma unroll
  for (int j = 0; j < 4; ++j) {       // prologue: steps 0..3
    a0[j] = *(const intx4*)(pA0 + j * FRAG);
    a1[j] = *(const intx4*)(pA1 + j * FRAG);
    b0[j] = *(const intx4*)(pB0 + j * FRAG);
    b1[j] = *(const intx4*)(pB1 + j * FRAG);
  }
  pA0 += 4 * FRAG; pA1 += 4 * FRAG; pB0 += 4 * FRAG; pB1 += 4 * FRAG;

  #define STEP(j)                                                             \
    {                                                                         \
      const intx8 A0 = widen(a0[j]), A1 = widen(a1[j]);                       \
      const intx8 B0 = widen(b0[j]), B1 = widen(b1[j]);                       \
      acc[0][0] = __builtin_amdgcn_mfma_scale_f32_32x32x64_f8f6f4(            \
          A0, B0, acc[0][0], 4, 4, 0, 127, 0, 127);                           \
      acc[0][1] = __builtin_amdgcn_mfma_scale_f32_32x32x64_f8f6f4(            \
          A0, B1, acc[0][1], 4, 4, 0, 127, 0, 127);                           \
      acc[1][0] = __builtin_amdgcn_mfma_scale_f32_32x32x64_f8f6f4(            \
          A1, B0, acc[1][0], 4, 4, 0, 127, 0, 127);                           \
      acc[1][1] = __builtin_amdgcn_mfma_scale_f32_32x32x64_f8f6f4(            \
          A1, B1, acc[1][1], 4, 4, 0, 127, 0, 127);                           \
    }
  #define PREF(j)                                                             \
    {                                                                         \
      a0[j] = *(const intx4*)(pA0 + (j) * FRAG);                              \
      a1[j] = *(const intx4*)(pA1 + (j) * FRAG);                              \
      b0[j] = *(const intx4*)(pB0 + (j) * FRAG);                              \
      b1[j] = *(const intx4*)(pB1 + (j) * FRAG);                              \
    }

  // 31 bodies x 4 steps = steps 0..123 consumed, prefetch up to step 127
  for (int i = 0; i < 31; ++i) {
    STEP(0) PREF(0)
    STEP(1) PREF(1)
    STEP(2) PREF(2)
    STEP(3) PREF(3)
    pA0 += 4 * FRAG; pA1 += 4 * FRAG; pB0 += 4 * FRAG; pB1 += 4 * FRAG;
  }
  STEP(0) STEP(1) STEP(2) STEP(3)     // steps 124..127

  // epilogue (verified rounds 5-9): sim = -inter/(|A_i|+|A_j|-inter) + mirror.
  // 32x32 C layout: col = lane&31, row = (reg&3) + 8*(reg>>2) + 4*(lane>>5).
  #pragma unroll
  for (int tm = 0; tm < 2; ++tm) {
    const int rowb = iB + tm * 32 + 4 * khalf;
    #pragma unroll
    for (int tn = 0; tn < 2; ++tn) {
      const int colb = jB + tn * 32 + r31;
      const float sj = sizes[colb];
      #pragma unroll
      for (int q = 0; q < 4; ++q) {           // reg quads: rows rq..rq+3
        const int rq = rowb + 8 * q;
        floatx4 tv;
        #pragma unroll
        for (int j = 0; j < 4; ++j) {
          const float inter = acc[tm][tn][4 * q + j];
          const float u = sizes[rq + j] + sj - inter;
          tv[j] = (u != 0.f) ? (-inter / u) : 0.f;
        }
        __builtin_nontemporal_store(tv[0], &out[(size_t)(rq + 0) * B_ROWS + colb]);
        __builtin_nontemporal_store(tv[1], &out[(size_t)(rq + 1) * B_ROWS + colb]);
        __builtin_nontemporal_store(tv[2], &out[(size_t)(rq + 2) * B_ROWS + colb]);
        __builtin_nontemporal_store(tv[3], &out[(size_t)(rq + 3) * B_ROWS + colb]);
        // mirrored: 4 row-values contiguous in the transposed row (16B-aligned)
        __builtin_nontemporal_store(tv, (floatx4*)&out[(size_t)colb * B_ROWS + rq]);
      }
    }
  }
}

// ---------------- launcher ---------------------------------------------------
extern "C" void kernel_launch(void* const* d_in, const int* in_sizes, int n_in,
                              void* d_out, int out_size, void* d_ws, size_t ws_size,
                              hipStream_t stream) {
  const int* features = (const int*)d_in[0];
  float* out = (float*)d_out;
  uint32_t* P = (uint32_t*)d_ws;                    // 16 MB fp4 panel layout
  float* sizes = (float*)((char*)d_ws + (size_t)(B_ROWS / 32) * GBYTES);

  presence_kernel<<<B_ROWS / 4, 256, 0, stream>>>(features, P, sizes);
  gemm_kernel<<<528, 256, 0, stream>>>((const unsigned char*)P, sizes, out);
}

// Round 11
// 166.076 us; speedup vs baseline: 1.3619x; 1.0098x over previous
//
#include <hip/hip_runtime.h>
#include <stdint.h>

#define B_ROWS 4096
#define L_FEAT 256
#define VOCAB  8192
#define FRAG   1024             // one MFMA operand fragment: 32 rows x 64 elems
#define KCHUNKS (VOCAB / 64)    // 128 fragments along K per 32-row group
#define GBYTES  (KCHUNKS * FRAG)  // 128 KB per 32-row group
#define NSTEP  128              // K steps of 64 elems

typedef __attribute__((ext_vector_type(4)))  int   intx4;
typedef __attribute__((ext_vector_type(8)))  int   intx8;
typedef __attribute__((ext_vector_type(4)))  float floatx4;
typedef __attribute__((ext_vector_type(16))) float floatx16;

// fp4 operand: HW reads only v[0:3] of the 8-reg A/B field (FMT=4); upper
// half undef (verified r9/r10: passed, absmax 0).
__device__ __forceinline__ intx8 widen(intx4 v) {
  return __builtin_shufflevector(v, v, 0, 1, 2, 3, -1, -1, -1, -1);
}

// ---------------- kernel 1: presence in PANEL (MFMA-fragment) layout ---------
// (verified round 10) fragment (g,kc) holds rows [32g,32g+32) x k-elems
// [64kc,64kc+64), byte = (g*128+kc)*1024 + ((row&31)+32*half)*16.
__global__ __launch_bounds__(256) void presence_kernel(
    const int* __restrict__ f,
    uint32_t* __restrict__ P,     // fp4 presence, panel layout (16 MB)
    float* __restrict__ sizes) {
  __shared__ uint32_t rw[4][VOCAB / 8];   // 4 x 1024 words = 16 KB
  const int rbase = blockIdx.x * 4;
  const int tid = threadIdx.x;

  uint4* rp4 = (uint4*)&rw[0][0];         // 1024 uint4
  const uint4 z = make_uint4(0u, 0u, 0u, 0u);
  #pragma unroll
  for (int j = 0; j < 4; ++j) rp4[tid + j * 256] = z;
  __syncthreads();

  #pragma unroll
  for (int r = 0; r < 4; ++r) {
    const int v = f[(rbase + r) * L_FEAT + tid];     // coalesced
    atomicOr(&rw[r][v >> 3], 0x2u << ((v & 7) * 4)); // fp4 nibble 1.0; dups ok
  }
  __syncthreads();

  // panel write: 1024 chunks of 16B; chunk c -> kc=c>>3, half=(c>>2)&1, ro=c&3
  const int g = blockIdx.x >> 3;
  const int slotBase = (blockIdx.x & 7) * 4;   // row slot within 32-row group
  char* Pg = (char*)P + (size_t)g * GBYTES;
  #pragma unroll
  for (int j = 0; j < 4; ++j) {
    const int c  = tid + j * 256;
    const int kc = c >> 3, h = (c >> 2) & 1, ro = c & 3;
    const uint4 val = *(const uint4*)&rw[ro][kc * 8 + h * 4];
    *(uint4*)(Pg + kc * FRAG + (slotBase + ro + 32 * h) * 16) = val;
  }

  // sizes: wave w popcounts row w
  const int w = tid >> 6, lane = tid & 63;
  const uint4* sp4 = (const uint4*)&rw[w][0];        // 256 uint4
  int cnt = 0;
  #pragma unroll
  for (int q = 0; q < 4; ++q) {
    const uint4 x = sp4[lane + q * 64];
    cnt += __popc(x.x & 0x22222222u) + __popc(x.y & 0x22222222u) +
           __popc(x.z & 0x22222222u) + __popc(x.w & 0x22222222u);
  }
  #pragma unroll
  for (int off = 32; off > 0; off >>= 1) cnt += __shfl_down(cnt, off);
  if (lane == 0) sizes[rbase + w] = (float)cnt;
}

// ---------------- kernel 2: inter = P·P^T (fp4 MX MFMA) + Jaccard + mirror ---
// Round-11 = round-10 winner (panel layout, no LDS, no barriers) + two fixes:
//   * prefetch ring 4 -> 8 (32 loads in flight, covers ~2000 cyc wall >
//     L3-hit latency ~900; r10's depth-4 left B-panel L3 hits exposed).
//   * supertile decode: 4x4-block supertiles (A 2MB + B 2MB fits an XCD L2);
//     XCD swizzle outer so one XCD's 66-bid chunk walks ~4 supertiles
//     instead of a 16-MB row of B panels (r10 FETCH=84MB = L3 refetch).
__global__ __launch_bounds__(256, 2) void gemm_kernel(
    const unsigned char* __restrict__ P,
    const float* __restrict__ sizes,
    float* __restrict__ out) {
  // XCD swizzle (528 = 8*66 -> bijective)
  int bid = blockIdx.x;
  bid = (bid & 7) * 66 + (bid >> 3);
  // supertile-triangle decode: 8x8 supertiles of 4x4 blocks, bx >= by.
  // row sy: diagonal ST (10 blocks) + (7-sy) full STs (16 each).
  int b = bid, sy = 0, rem = 122;               // 10 + 16*7
  while (b >= rem) { b -= rem; ++sy; rem -= 16; }
  int by, bx;
  if (b < 10) {                                 // diagonal supertile interior
    int ly = 0, r2 = 4;
    while (b >= r2) { b -= r2; ++ly; --r2; }
    by = sy * 4 + ly; bx = sy * 4 + ly + b;
  } else {
    const int t = b - 10;
    const int sx = sy + 1 + (t >> 4);
    const int l = t & 15;
    by = sy * 4 + (l >> 2); bx = sx * 4 + (l & 3);
  }

  const int tid  = threadIdx.x;
  const int wave = tid >> 6, lane = tid & 63;
  const int wm = wave >> 1, wn = wave & 1;   // 2x2 wave grid, each wave 64x64
  const int r31 = lane & 31, khalf = lane >> 5;

  const int iB = by * 128 + wm * 64;   // this wave's output rows
  const int jB = bx * 128 + wn * 64;   // this wave's output cols

  // fragment base pointers (advance +8*FRAG per body)
  const unsigned char* pA0 = P + (size_t)(by * 4 + wm * 2 + 0) * GBYTES + lane * 16;
  const unsigned char* pA1 = P + (size_t)(by * 4 + wm * 2 + 1) * GBYTES + lane * 16;
  const unsigned char* pB0 = P + (size_t)(bx * 4 + wn * 2 + 0) * GBYTES + lane * 16;
  const unsigned char* pB1 = P + (size_t)(bx * 4 + wn * 2 + 1) * GBYTES + lane * 16;

  floatx16 acc[2][2];
  #pragma unroll
  for (int ai = 0; ai < 2; ++ai)
    #pragma unroll
    for (int ci = 0; ci < 2; ++ci)
      #pragma unroll
      for (int e = 0; e < 16; ++e) acc[ai][ci][e] = 0.f;

  intx4 a0[8], a1[8], b0[8], b1[8];   // 8-step register ring, literal indices

  #pragma unroll
  for (int j = 0; j < 8; ++j) {       // prologue: steps 0..7
    a0[j] = *(const intx4*)(pA0 + j * FRAG);
    a1[j] = *(const intx4*)(pA1 + j * FRAG);
    b0[j] = *(const intx4*)(pB0 + j * FRAG);
    b1[j] = *(const intx4*)(pB1 + j * FRAG);
  }
  pA0 += 8 * FRAG; pA1 += 8 * FRAG; pB0 += 8 * FRAG; pB1 += 8 * FRAG;

  #define STEP(j)                                                             \
    {                                                                         \
      const intx8 A0 = widen(a0[j]), A1 = widen(a1[j]);                       \
      const intx8 B0 = widen(b0[j]), B1 = widen(b1[j]);                       \
      acc[0][0] = __builtin_amdgcn_mfma_scale_f32_32x32x64_f8f6f4(            \
          A0, B0, acc[0][0], 4, 4, 0, 127, 0, 127);                           \
      acc[0][1] = __builtin_amdgcn_mfma_scale_f32_32x32x64_f8f6f4(            \
          A0, B1, acc[0][1], 4, 4, 0, 127, 0, 127);                           \
      acc[1][0] = __builtin_amdgcn_mfma_scale_f32_32x32x64_f8f6f4(            \
          A1, B0, acc[1][0], 4, 4, 0, 127, 0, 127);                           \
      acc[1][1] = __builtin_amdgcn_mfma_scale_f32_32x32x64_f8f6f4(            \
          A1, B1, acc[1][1], 4, 4, 0, 127, 0, 127);                           \
    }
  #define PREF(j)                                                             \
    {                                                                         \
      a0[j] = *(const intx4*)(pA0 + (j) * FRAG);                              \
      a1[j] = *(const intx4*)(pA1 + (j) * FRAG);                              \
      b0[j] = *(const intx4*)(pB0 + (j) * FRAG);                              \
      b1[j] = *(const intx4*)(pB1 + (j) * FRAG);                              \
    }

  // 15 bodies x 8 steps = steps 0..119 consumed, prefetch up to step 127
  for (int i = 0; i < 15; ++i) {
    STEP(0) PREF(0)
    STEP(1) PREF(1)
    STEP(2) PREF(2)
    STEP(3) PREF(3)
    STEP(4) PREF(4)
    STEP(5) PREF(5)
    STEP(6) PREF(6)
    STEP(7) PREF(7)
    pA0 += 8 * FRAG; pA1 += 8 * FRAG; pB0 += 8 * FRAG; pB1 += 8 * FRAG;
  }
  STEP(0) STEP(1) STEP(2) STEP(3)     // steps 120..127
  STEP(4) STEP(5) STEP(6) STEP(7)

  // epilogue (verified rounds 5-10): sim = -inter/(|A_i|+|A_j|-inter) + mirror.
  // 32x32 C layout: col = lane&31, row = (reg&3) + 8*(reg>>2) + 4*(lane>>5).
  #pragma unroll
  for (int tm = 0; tm < 2; ++tm) {
    const int rowb = iB + tm * 32 + 4 * khalf;
    #pragma unroll
    for (int tn = 0; tn < 2; ++tn) {
      const int colb = jB + tn * 32 + r31;
      const float sj = sizes[colb];
      #pragma unroll
      for (int q = 0; q < 4; ++q) {           // reg quads: rows rq..rq+3
        const int rq = rowb + 8 * q;
        floatx4 tv;
        #pragma unroll
        for (int j = 0; j < 4; ++j) {
          const float inter = acc[tm][tn][4 * q + j];
          const float u = sizes[rq + j] + sj - inter;
          tv[j] = (u != 0.f) ? (-inter / u) : 0.f;
        }
        __builtin_nontemporal_store(tv[0], &out[(size_t)(rq + 0) * B_ROWS + colb]);
        __builtin_nontemporal_store(tv[1], &out[(size_t)(rq + 1) * B_ROWS + colb]);
        __builtin_nontemporal_store(tv[2], &out[(size_t)(rq + 2) * B_ROWS + colb]);
        __builtin_nontemporal_store(tv[3], &out[(size_t)(rq + 3) * B_ROWS + colb]);
        // mirrored: 4 row-values contiguous in the transposed row (16B-aligned)
        __builtin_nontemporal_store(tv, (floatx4*)&out[(size_t)colb * B_ROWS + rq]);
      }
    }
  }
}

// ---------------- launcher ---------------------------------------------------
extern "C" void kernel_launch(void* const* d_in, const int* in_sizes, int n_in,
                              void* d_out, int out_size, void* d_ws, size_t ws_size,
                              hipStream_t stream) {
  const int* features = (const int*)d_in[0];
  float* out = (float*)d_out;
  uint32_t* P = (uint32_t*)d_ws;                    // 16 MB fp4 panel layout
  float* sizes = (float*)((char*)d_ws + (size_t)(B_ROWS / 32) * GBYTES);

  presence_kernel<<<B_ROWS / 4, 256, 0, stream>>>(features, P, sizes);
  gemm_kernel<<<528, 256, 0, stream>>>((const unsigned char*)P, sizes, out);
}